// Round 9
// baseline (427.682 us; speedup 1.0000x reference)
//
#include <hip/hip_runtime.h>
#include <stdint.h>
#include <math.h>

#define DIMC 2048
#define NHEADS 16
#define HDIM 128
#define TSEQ 2048
#define NTOK 4096   // B*T

using bf16x8 = __attribute__((ext_vector_type(8))) short;
using f32x4  = __attribute__((ext_vector_type(4))) float;

typedef __attribute__((address_space(1))) const void gas_void;
typedef __attribute__((address_space(3))) void las_void;

static __device__ __forceinline__ unsigned short f2b(float f) {
  union { float f; unsigned int u; } a; a.f = f;
  unsigned int u = a.u;
  u = (u + 0x7fffu + ((u >> 16) & 1u)) >> 16;   // RNE
  return (unsigned short)u;
}
static __device__ __forceinline__ float b2f(unsigned short s) {
  union { unsigned int u; float f; } a; a.u = ((unsigned int)s) << 16;
  return a.f;
}

// -------- input dtype detection: bf16 vs fp32, from x's bit patterns --------
__global__ void detect_dtype(const unsigned short* __restrict__ xs,
                             int* __restrict__ flag)
{
  const int lane = threadIdx.x;          // 64 threads
  const unsigned short u = xs[2 * lane];
  const int e = (u >> 7) & 0xFF;
  const bool plausible = (e >= 112) && (e <= 135);
  const unsigned long long m = __ballot(plausible);
  if (lane == 0) *flag = (__popcll(m) >= 32) ? 1 : 0;
}

// ---------------- ternary dequant core (dtype-flag branched) --------------
static __device__ __forceinline__ void dequant_one(
    const void* __restrict__ w, unsigned short* __restrict__ o,
    int grp, int lane, int isbf16)
{
  float a, bq;
  if (isbf16) {
    const unsigned int pk =
        ((const unsigned int*)((const unsigned short*)w + (long)grp * 128))[lane];
    a  = b2f((unsigned short)(pk & 0xffffu));
    bq = b2f((unsigned short)(pk >> 16));
  } else {
    const float2 v = ((const float2*)((const float*)w + (long)grp * 128))[lane];
    a = v.x; bq = v.y;
  }
  double s = fabs((double)a) + fabs((double)bq);
  #pragma unroll
  for (int off = 1; off < 64; off <<= 1) s += __shfl_xor(s, off);
  double scale = s * (1.0 / 128.0);
  if (scale < 1e-8) scale = 1e-8;
  const float fs = (float)scale;
  const double wn0 = (double)a / scale;
  const double wn1 = (double)bq / scale;
  const float q0 = (wn0 > 0.5) ? fs : ((wn0 < -0.5) ? -fs : 0.0f);
  const float q1 = (wn1 > 0.5) ? fs : ((wn1 < -0.5) ? -fs : 0.0f);
  const unsigned int opk = (unsigned int)f2b(q0) | ((unsigned int)f2b(q1) << 16);
  ((unsigned int*)o)[(long)grp * 64 + lane] = opk;
}

__global__ void __launch_bounds__(256) dequant_auto(
    const void* __restrict__ w, unsigned short* __restrict__ o,
    const int* __restrict__ flag)
{
  const int wave = threadIdx.x >> 6, lane = threadIdx.x & 63;
  dequant_one(w, o, blockIdx.x * 4 + wave, lane, *flag);
}

// fused dequant of wq/wk/wv into one row-stacked [6144][2048] buffer
__global__ void __launch_bounds__(256) dequant3(
    const void* __restrict__ w0, const void* __restrict__ w1,
    const void* __restrict__ w2, unsigned short* __restrict__ o,
    const int* __restrict__ flag)
{
  const int wave = threadIdx.x >> 6, lane = threadIdx.x & 63;
  const void* w = (blockIdx.y == 0) ? w0 : (blockIdx.y == 1) ? w1 : w2;
  unsigned short* oo = o + (long)blockIdx.y * DIMC * DIMC;
  dequant_one(w, oo, blockIdx.x * 4 + wave, lane, *flag);
}

// ---------------- x -> bf16 (cast fp32 or copy bf16, flag-branched) -------
__global__ void __launch_bounds__(256) cast_auto(
    const void* __restrict__ x, unsigned short* __restrict__ o,
    const int* __restrict__ flag)
{
  const int i = (blockIdx.x * 256 + threadIdx.x) * 4;
  if (*flag) {
    *(ushort4*)(o + i) = *(const ushort4*)((const unsigned short*)x + i);
  } else {
    const float4 v = *(const float4*)((const float*)x + i);
    ushort4 u;
    u.x = f2b(v.x); u.y = f2b(v.y); u.z = f2b(v.z); u.w = f2b(v.w);
    *(ushort4*)(o + i) = u;
  }
}

// ---------------- bf16 GEMM, C[m,n] = sum_k A[m,k]*B[n,k] (B^T input) -----
// BK=64 m97-derived structure. Wave col map: ncol(nt) = (wave&1)*32 +
// (nt&1)*16 + (nt>>1)*64 (+c16) — a bijection (GEMM-legal) chosen so the
// RoPE partner cols (d, d+64) are acc[mt][nt] / acc[mt][nt+2]: rotation is
// pure in-register fp32 in the epilogue (ROPE template flag).
__device__ __forceinline__ void storeOne(float* C, long i, float v) { C[i] = v; }
__device__ __forceinline__ void storeOne(unsigned short* C, long i, float v) { C[i] = f2b(v); }

template <typename OUTT, bool ROPE>
static __device__ __forceinline__ void gemm_tile(
    const unsigned short* __restrict__ A, const unsigned short* __restrict__ B,
    OUTT* __restrict__ C, int m0, int n0, int Nc, int K,
    unsigned short* As, unsigned short* Bs)   // each 128*64 elems
{
  const int tid = threadIdx.x;
  const int wave = tid >> 6;
  const int lane = tid & 63;
  const int wr = (wave >> 1) * 64;
  const int wc2 = (wave & 1) * 32;
  const int c16 = lane & 15, q4 = lane >> 4;

  f32x4 acc[4][4];
  #pragma unroll
  for (int i = 0; i < 4; i++)
    #pragma unroll
    for (int j = 0; j < 4; j++)
      acc[i][j] = (f32x4){0.f, 0.f, 0.f, 0.f};

  const int srow = tid >> 2;            // 0..63
  const int scol = (tid & 3) * 8;       // 16 B chunk within a 32-col half
  const unsigned short* ga = A + (long)(m0 + srow) * K + scol;
  const unsigned short* gb = B + (long)(n0 + srow) * K + scol;

  for (int k0 = 0; k0 < K; k0 += 64) {
    #pragma unroll
    for (int h = 0; h < 2; h++)
      #pragma unroll
      for (int i = 0; i < 2; i++) {
        __builtin_amdgcn_global_load_lds(
            (gas_void*)(ga + (long)i * 64 * K + k0 + h * 32),
            (las_void*)(As + h * 4096 + i * 2048 + wave * 512), 16, 0, 0);
        __builtin_amdgcn_global_load_lds(
            (gas_void*)(gb + (long)i * 64 * K + k0 + h * 32),
            (las_void*)(Bs + h * 4096 + i * 2048 + wave * 512), 16, 0, 0);
      }
    __syncthreads();
    #pragma unroll
    for (int kc = 0; kc < 2; kc++) {
      bf16x8 af[4], bfr[4];
      #pragma unroll
      for (int t = 0; t < 4; t++) {
        const int nrow = wc2 + (t & 1) * 16 + (t >> 1) * 64 + c16;
        af[t]  = *(const bf16x8*)(As + kc * 4096 + (wr + t * 16 + c16) * 32 + q4 * 8);
        bfr[t] = *(const bf16x8*)(Bs + kc * 4096 + nrow * 32 + q4 * 8);
      }
      #pragma unroll
      for (int mt = 0; mt < 4; mt++)
        #pragma unroll
        for (int nt = 0; nt < 4; nt++)
          acc[mt][nt] = __builtin_amdgcn_mfma_f32_16x16x32_bf16(af[mt], bfr[nt], acc[mt][nt], 0, 0, 0);
    }
    __syncthreads();
  }

  if (ROPE) {
    // cols within slab: j (first half) at nt, j+64 at nt+2; j = wc2+(nt&1)*16+c16
    float invf[2];
    #pragma unroll
    for (int j2 = 0; j2 < 2; j2++)
      invf[j2] = __expf(-0.14391565f * (float)(wc2 + j2 * 16 + c16));
    #pragma unroll
    for (int mt = 0; mt < 4; mt++)
      #pragma unroll
      for (int r = 0; r < 4; r++) {
        const int m = m0 + wr + mt * 16 + q4 * 4 + r;
        const float t = (float)(m & (TSEQ - 1));
        #pragma unroll
        for (int j2 = 0; j2 < 2; j2++) {
          const float ang = t * invf[j2];
          const float cs = __cosf(ang), sn = __sinf(ang);
          const float x1 = acc[mt][j2][r], x2 = acc[mt][j2 + 2][r];
          acc[mt][j2][r]     = x1 * cs - x2 * sn;
          acc[mt][j2 + 2][r] = x1 * sn + x2 * cs;
        }
      }
  }

  // C/D layout (m89-verified): n = lane&15, m = (lane>>4)*4 + reg
  #pragma unroll
  for (int mt = 0; mt < 4; mt++) {
    const int m = m0 + wr + mt * 16 + q4 * 4;
    #pragma unroll
    for (int nt = 0; nt < 4; nt++) {
      const int n = wc2 + (nt & 1) * 16 + (nt >> 1) * 64 + c16;  // caller pre-offsets C
      #pragma unroll
      for (int r = 0; r < 4; r++)
        storeOne(C, (long)(m + r) * Nc + n, acc[mt][nt][r]);
    }
  }
}

template <typename OUTT>
__global__ void __launch_bounds__(256) gemm_bt(
    const unsigned short* __restrict__ A, const unsigned short* __restrict__ B,
    OUTT* __restrict__ C, int M, int N, int K)
{
  __shared__ unsigned short As[128 * 64];
  __shared__ unsigned short Bs[128 * 64];
  gemm_tile<OUTT, false>(A, B, C + blockIdx.x * 128, blockIdx.y * 128,
                         blockIdx.x * 128, N, K, As, Bs);
}

// fused QKV + RoPE: B row-stacked [6144][2048]; 128-col slab = one head.
// RoPE applied in-epilogue for Q and K slabs (n0<4096), not V.
__global__ void __launch_bounds__(256) gemm_qkv(
    const unsigned short* __restrict__ A, const unsigned short* __restrict__ B,
    unsigned short* __restrict__ C0, unsigned short* __restrict__ C1,
    unsigned short* __restrict__ C2, int K)
{
  __shared__ unsigned short As[128 * 64];
  __shared__ unsigned short Bs[128 * 64];
  const int n0 = blockIdx.x * 128;                 // 0..6143
  unsigned short* Cb = (n0 < 2048) ? C0 : (n0 < 4096) ? C1 : C2;
  if (n0 < 4096)
    gemm_tile<unsigned short, true>(A, B, Cb + (n0 & 2047), blockIdx.y * 128,
                                    n0, DIMC, K, As, Bs);
  else
    gemm_tile<unsigned short, false>(A, B, Cb + (n0 & 2047), blockIdx.y * 128,
                                     n0, DIMC, K, As, Bs);
}

// ---------------- flash attention v3 (causal), bf16 MFMA ----------------
// v3 + balanced qt pairing: blocks 0..255 carry qt 15..8, blocks 256..511
// carry qt 0..7 -> each CU's two resident blocks sum to ~constant work.
#define FA_M 16.0f
__global__ void __launch_bounds__(256) fattn(
    const unsigned short* __restrict__ Q,
    const unsigned short* __restrict__ K,
    const unsigned short* __restrict__ V,
    unsigned short* __restrict__ Y)
{
  __shared__ unsigned short SU[9216];       // 18432 B union (Ks | Ps)
  __shared__ unsigned short VT[128 * 72];   // 18432 B
  __shared__ float red[4][32];

  const int tid = threadIdx.x, wave = tid >> 6, lane = tid & 63;
  const int idx = blockIdx.x;               // 512 blocks
  const int qt = (idx < 256) ? (15 - (idx >> 5)) : ((idx - 256) >> 5);
  const int bh = idx & 31;
  const int b = bh >> 4, h = bh & 15;
  const int qbase = qt * 128;
  const int qw = wave * 32;
  const int c = lane & 15, g = lane >> 4;
  const long tokbase = (long)b * TSEQ;
  const int col0 = h * HDIM;

  bf16x8 qf[2][4];
  #pragma unroll
  for (int qq = 0; qq < 2; qq++) {
    const unsigned short* qp =
        Q + (tokbase + qbase + qw + qq * 16 + c) * DIMC + col0 + g * 8;
    #pragma unroll
    for (int kc = 0; kc < 4; kc++) qf[qq][kc] = *(const bf16x8*)(qp + kc * 32);
  }

  f32x4 od[8][2];
  #pragma unroll
  for (int dt = 0; dt < 8; dt++)
    #pragma unroll
    for (int qq = 0; qq < 2; qq++)
      od[dt][qq] = (f32x4){0.f, 0.f, 0.f, 0.f};
  float lpart[2][4];
  #pragma unroll
  for (int qq = 0; qq < 2; qq++)
    #pragma unroll
    for (int r = 0; r < 4; r++) lpart[qq][r] = 0.0f;

  const int ksr = tid >> 2, ksc = (tid & 3) * 32;
  const int vk0 = (tid & 31) * 2, vd0 = (tid >> 5) * 16;

  const float SC = 0.088388347648318447f;  // 1/sqrt(128)
  const int nkt = 2 * qt + 2;

  float4 kr0, kr1, kr2, kr3;
  bf16x8 va0, va1, vb0, vb1;
  {
    const unsigned short* src = K + (tokbase + ksr) * DIMC + col0 + ksc;
    kr0 = ((const float4*)src)[0]; kr1 = ((const float4*)src)[1];
    kr2 = ((const float4*)src)[2]; kr3 = ((const float4*)src)[3];
    const unsigned short* s0 = V + (tokbase + vk0) * DIMC + col0 + vd0;
    const unsigned short* s1 = s0 + DIMC;
    va0 = *(const bf16x8*)(s0); va1 = *(const bf16x8*)(s0 + 8);
    vb0 = *(const bf16x8*)(s1); vb1 = *(const bf16x8*)(s1 + 8);
  }

  for (int kt = 0; kt < nkt; kt++) {
    const int kb = kt * 64;
    __syncthreads();   // A: prev-iter readers done with SU/VT
    {
      float4* dst = (float4*)&SU[ksr * 136 + ksc];
      dst[0] = kr0; dst[1] = kr1; dst[2] = kr2; dst[3] = kr3;
    }
    {
      #pragma unroll
      for (int dd = 0; dd < 8; dd++) {
        const unsigned int p0 =
            (unsigned int)(unsigned short)va0[dd] |
            ((unsigned int)(unsigned short)vb0[dd] << 16);
        *(unsigned int*)&VT[(vd0 + dd) * 72 + vk0] = p0;
      }
      #pragma unroll
      for (int dd = 0; dd < 8; dd++) {
        const unsigned int p1 =
            (unsigned int)(unsigned short)va1[dd] |
            ((unsigned int)(unsigned short)vb1[dd] << 16);
        *(unsigned int*)&VT[(vd0 + 8 + dd) * 72 + vk0] = p1;
      }
    }
    __syncthreads();   // B: staging visible

    if (kt + 1 < nkt) {
      const int kb2 = kb + 64;
      const unsigned short* src = K + (tokbase + kb2 + ksr) * DIMC + col0 + ksc;
      kr0 = ((const float4*)src)[0]; kr1 = ((const float4*)src)[1];
      kr2 = ((const float4*)src)[2]; kr3 = ((const float4*)src)[3];
      const unsigned short* s0 = V + (tokbase + kb2 + vk0) * DIMC + col0 + vd0;
      const unsigned short* s1 = s0 + DIMC;
      va0 = *(const bf16x8*)(s0); va1 = *(const bf16x8*)(s0 + 8);
      vb0 = *(const bf16x8*)(s1); vb1 = *(const bf16x8*)(s1 + 8);
    }

    f32x4 sacc[2][4];
    #pragma unroll
    for (int qq = 0; qq < 2; qq++)
      #pragma unroll
      for (int nt = 0; nt < 4; nt++) sacc[qq][nt] = (f32x4){0.f, 0.f, 0.f, 0.f};
    #pragma unroll
    for (int kc = 0; kc < 4; kc++) {
      bf16x8 bk[4];
      #pragma unroll
      for (int nt = 0; nt < 4; nt++)
        bk[nt] = *(const bf16x8*)&SU[(nt * 16 + c) * 136 + kc * 32 + g * 8];
      #pragma unroll
      for (int qq = 0; qq < 2; qq++)
        #pragma unroll
        for (int nt = 0; nt < 4; nt++)
          sacc[qq][nt] = __builtin_amdgcn_mfma_f32_16x16x32_bf16(
              qf[qq][kc], bk[nt], sacc[qq][nt], 0, 0, 0);
    }
    __syncthreads();   // C: Ks reads done before Ps overwrites SU

    #pragma unroll
    for (int qq = 0; qq < 2; qq++)
      #pragma unroll
      for (int r = 0; r < 4; r++) {
        const int qg = qbase + qw + qq * 16 + g * 4 + r;
        #pragma unroll
        for (int nt = 0; nt < 4; nt++) {
          const int kg = kb + nt * 16 + c;
          const float sv = sacc[qq][nt][r] * SC - FA_M;
          const float p = (kg > qg) ? 0.0f : __expf(sv);
          lpart[qq][r] += p;
          SU[(wave * 32 + qq * 16 + g * 4 + r) * 72 + nt * 16 + c] = f2b(p);
        }
      }

    #pragma unroll
    for (int kc = 0; kc < 2; kc++) {
      bf16x8 pb[2];
      #pragma unroll
      for (int qq = 0; qq < 2; qq++)
        pb[qq] = *(const bf16x8*)&SU[(wave * 32 + qq * 16 + c) * 72 + kc * 32 + g * 8];
      #pragma unroll
      for (int dt = 0; dt < 8; dt++) {
        bf16x8 va = *(const bf16x8*)&VT[(dt * 16 + c) * 72 + kc * 32 + g * 8];
        #pragma unroll
        for (int qq = 0; qq < 2; qq++)
          od[dt][qq] = __builtin_amdgcn_mfma_f32_16x16x32_bf16(
              va, pb[qq], od[dt][qq], 0, 0, 0);
      }
    }
  }

  #pragma unroll
  for (int qq = 0; qq < 2; qq++)
    #pragma unroll
    for (int r = 0; r < 4; r++) {
      float l = lpart[qq][r];
      #pragma unroll
      for (int off = 1; off < 16; off <<= 1) l += __shfl_xor(l, off);
      lpart[qq][r] = l;
    }
  __syncthreads();
  if (c == 0) {
    #pragma unroll
    for (int qq = 0; qq < 2; qq++)
      #pragma unroll
      for (int r = 0; r < 4; r++)
        red[wave][qq * 16 + g * 4 + r] = 1.0f / lpart[qq][r];
  }
  __syncthreads();
  #pragma unroll
  for (int qq = 0; qq < 2; qq++) {
    const float linv = red[wave][qq * 16 + c];
    unsigned short* yp =
        Y + (tokbase + qbase + qw + qq * 16 + c) * DIMC + col0;
    #pragma unroll
    for (int dt = 0; dt < 8; dt++)
      #pragma unroll
      for (int r = 0; r < 4; r++)
        yp[dt * 16 + g * 4 + r] = f2b(od[dt][qq][r] * linv);
  }
}

extern "C" void kernel_launch(void* const* d_in, const int* in_sizes, int n_in,
                              void* d_out, int out_size, void* d_ws, size_t ws_size,
                              hipStream_t stream)
{
  const void* x  = d_in[0];
  const void* wq = d_in[1];
  const void* wk = d_in[2];
  const void* wv = d_in[3];
  const void* wo = d_in[4];
  float* out = (float*)d_out;

  char* ws = (char*)d_ws;
  const size_t MB = 1024 * 1024;
  unsigned short* wbuf = (unsigned short*)(ws + 0 * MB);   // 24 MB (QKV stacked; wo reuses first 8)
  unsigned short* xb   = (unsigned short*)(ws + 24 * MB);  // 16 MB
  unsigned short* Qb   = (unsigned short*)(ws + 40 * MB);  // 16 MB
  unsigned short* Kb   = (unsigned short*)(ws + 56 * MB);  // 16 MB
  unsigned short* Vb   = (unsigned short*)(ws + 72 * MB);  // 16 MB
  int* flag            = (int*)(ws + 88 * MB);             // 4 B
  unsigned short* Yb   = xb;   // x dead after QKV projection; alias.

  detect_dtype<<<dim3(1), 64, 0, stream>>>((const unsigned short*)x, flag);
  cast_auto<<<dim3(8192), 256, 0, stream>>>(x, xb, flag);
  dequant3<<<dim3(8192, 3), 256, 0, stream>>>(wq, wk, wv, wbuf, flag);
  gemm_qkv<<<dim3(48, 32), 256, 0, stream>>>(xb, wbuf, Qb, Kb, Vb, DIMC);
  fattn<<<dim3(512), 256, 0, stream>>>(Qb, Kb, Vb, Yb);
  dequant_auto<<<dim3(8192), 256, 0, stream>>>(wo, wbuf, flag);
  gemm_bt<float><<<dim3(16, 32), 256, 0, stream>>>(Yb, wbuf, out, NTOK, DIMC, DIMC);
}